// Round 10
// baseline (656.346 us; speedup 1.0000x reference)
//
#include <hip/hip_runtime.h>
#include <hip/hip_bf16.h>
#include <cstdint>
#include <cstddef>

// ---------------------------------------------------------------------------
// BidirectionalCrossAttention — MI355X bf16 MFMA implementation, round 10.
// Attention rewrite: KEY-SPLIT waves (valid because fixed-max softmax makes
// per-key-slice partial O / lsum exactly additive).
//   - each wave owns keys [t*256 + w*64, +64) of outer tile t (8 outer iters)
//   - K fragments: global->reg with ping-pong prefetch (never in LDS)
//   - V: 256-key tile staged in LDS (XOR-swizzled), each wave reads only its
//     own 64-key slice -> 1x read amplification, 16 barriers total
//   - end: cross-wave O/lsum reduction through LDS, wave 0 writes Y
// Compute maps (st, softmax, pa, pi, vf, epilogue indexing) = round-5 proven.
// XCD swizzle: all 64 q-blocks of one (bh,dir) share one XCD's L2 (r9-proven).
// ---------------------------------------------------------------------------

typedef __attribute__((ext_vector_type(4))) float f32x4;
typedef __attribute__((ext_vector_type(8))) short bf16x8;
typedef __attribute__((ext_vector_type(4))) short s16x4;
typedef __attribute__((ext_vector_type(4))) unsigned int u32x4;

__device__ __forceinline__ short f2bf(float f) {
  union { float f; unsigned u; } v; v.f = f;
  unsigned r = v.u + 0x7FFF + ((v.u >> 16) & 1);   // RNE
  return (short)(r >> 16);
}

__device__ __forceinline__ unsigned cvt_pk_bf16(float lo, float hi) {
  unsigned r;
  asm("v_cvt_pk_bf16_f32 %0, %1, %2" : "=v"(r) : "v"(lo), "v"(hi));
  return r;   // D[15:0]=bf16(lo), D[31:16]=bf16(hi)
}

__device__ __forceinline__ void async16(const void* g, void* l) {
  __builtin_amdgcn_global_load_lds(
      (__attribute__((address_space(1))) unsigned int*)(g),
      (__attribute__((address_space(3))) unsigned int*)(l),
      16, 0, 0);
}

// ---------------------------------------------------------------------------
// Fused fp32 -> bf16 conversion over the 8 inputs (round-4 proven).
// ---------------------------------------------------------------------------
__global__ __launch_bounds__(256)
void cvt_all(const float* __restrict__ x, const float* __restrict__ src,
             const float* __restrict__ qkw, const float* __restrict__ qksw,
             const float* __restrict__ vw, const float* __restrict__ vsw,
             const float* __restrict__ pw, const float* __restrict__ psw,
             short* __restrict__ out) {
  int i = blockIdx.x * 256 + threadIdx.x;
  const float* in; int local; float scale = 1.f;
  if (i < 1572864) {
    if (i < 786432) { in = x; local = i; } else { in = src; local = i - 786432; }
  } else if (i < 2162688) {
    if (i < 1867776) { in = qkw; local = i - 1572864; scale = 0.125f * 1.44269504f; }
    else             { in = qksw; local = i - 1867776; }
  } else if (i < 2457600) {
    if (i < 2310144) { in = vw; local = i - 2162688; } else { in = vsw; local = i - 2310144; }
  } else {
    if (i < 2605056) { in = pw; local = i - 2457600; } else { in = psw; local = i - 2605056; }
  }
  float4 v = ((const float4*)in)[local];
  s16x4 o = { f2bf(v.x * scale), f2bf(v.y * scale),
              f2bf(v.z * scale), f2bf(v.w * scale) };
  ((s16x4*)out)[i] = o;
}

// ---------------------------------------------------------------------------
// GEMM: out[row, f] = sum_c A[row,c] * W[f,c]   (K = 768, round-4 proven)
// Two independent problems per dispatch: sel = blockIdx.y >> 5.
// ---------------------------------------------------------------------------
enum { EPI_HEAD128 = 0, EPI_HEADT64 = 1, EPI_PROJ = 2 };

template<int EPI>
__global__ __launch_bounds__(256)
void gemm_bt2(const short* __restrict__ A0, const short* __restrict__ W0,
              short* __restrict__ ob0, const float* __restrict__ bias0,
              const short* __restrict__ A1, const short* __restrict__ W1,
              short* __restrict__ ob1, const float* __restrict__ bias1,
              float* __restrict__ outf) {
  __shared__ short As[128 * 32];
  __shared__ short Ws[128 * 32];

  const int sel = blockIdx.y >> 5;
  const int by  = blockIdx.y & 31;
  const short* A = sel ? A1 : A0;
  const short* W = sel ? W1 : W0;
  short* outb = sel ? ob1 : ob0;
  const float* bias = sel ? bias1 : bias0;
  const int outColOff = sel ? 768 : 0;

  const int tid  = threadIdx.x;
  const int lane = tid & 63, wid = tid >> 6;
  const int wr = wid >> 1, wc = wid & 1;
  const int rowBase = by << 7, colBase = blockIdx.x << 7;
  const int c = lane & 15, g = lane >> 4;

  const short* gA = A + (size_t)(rowBase + wid * 32 + (lane >> 2)) * 768 + (lane & 3) * 8;
  const short* gW = W + (size_t)(colBase + wid * 32 + (lane >> 2)) * 768 + (lane & 3) * 8;
  short* lA = As + wid * 32 * 32;
  short* lW = Ws + wid * 32 * 32;

  const short* rA = As + (wr * 64 + c) * 32 + g * 8;
  const short* rW = Ws + (wc * 64 + c) * 32 + g * 8;

  f32x4 acc[4][4] = {};

  for (int kt = 0; kt < 24; ++kt) {
    async16(gA,            lA);
    async16(gA + 16 * 768, lA + 16 * 32);
    async16(gW,            lW);
    async16(gW + 16 * 768, lW + 16 * 32);
    gA += 32; gW += 32;
    __syncthreads();
    bf16x8 af[4], wf[4];
#pragma unroll
    for (int i = 0; i < 4; ++i) af[i] = *(const bf16x8*)(rA + i * 512);
#pragma unroll
    for (int j = 0; j < 4; ++j) wf[j] = *(const bf16x8*)(rW + j * 512);
#pragma unroll
    for (int i = 0; i < 4; ++i)
#pragma unroll
      for (int j = 0; j < 4; ++j)
        acc[i][j] = __builtin_amdgcn_mfma_f32_16x16x32_bf16(af[i], wf[j], acc[i][j], 0, 0, 0);
    __syncthreads();
  }

  if (EPI == EPI_HEAD128) {
#pragma unroll
    for (int i = 0; i < 4; ++i) {
      int row = rowBase + wr * 64 + i * 16 + g * 4;
      int b = row >> 11, n = row & 2047;
#pragma unroll
      for (int j = 0; j < 4; ++j) {
        int f = colBase + wc * 64 + j * 16 + c;
        int h = f >> 7, d = f & 127;
        short* p = outb + ((size_t)(b * 12 + h) * 2048 + n) * 128 + d;
#pragma unroll
        for (int r = 0; r < 4; ++r) p[(size_t)r * 128] = f2bf(acc[i][j][r]);
      }
    }
  } else if (EPI == EPI_HEADT64) {
#pragma unroll
    for (int i = 0; i < 4; ++i) {
      int row = rowBase + wr * 64 + i * 16 + g * 4;
      int b = row >> 11, n = row & 2047;
#pragma unroll
      for (int j = 0; j < 4; ++j) {
        int f = colBase + wc * 64 + j * 16 + c;
        int h = f >> 6, d = f & 63;
        s16x4 o4 = { f2bf(acc[i][j][0]), f2bf(acc[i][j][1]),
                     f2bf(acc[i][j][2]), f2bf(acc[i][j][3]) };
        *(s16x4*)(outb + ((size_t)(b * 12 + h) * 64 + d) * 2048 + n) = o4;
      }
    }
  } else {  // EPI_PROJ
#pragma unroll
    for (int j = 0; j < 4; ++j) {
      int colj = colBase + wc * 64 + j * 16 + c;
      float bv = bias[colj];
#pragma unroll
      for (int i = 0; i < 4; ++i) {
        int row = rowBase + wr * 64 + i * 16 + g * 4;
#pragma unroll
        for (int r = 0; r < 4; ++r)
          outf[(size_t)(row + r) * 1536 + outColOff + colj] = acc[i][j][r] + bv;
      }
    }
  }
}

// ---------------------------------------------------------------------------
// Flash cross-attention, key-split waves. Block = 32 q rows; wave w covers
// keys [t*256 + w*64, +64) per outer iter t (8 iters). Grid (64, 48).
//   Q : [BH, 2048, 128] bf16   K : [BH, 2048, 128] bf16
//   Vt: [BH, 64, 2048]  bf16 (V transposed)
//   Y : [B, 2048, 768]  bf16, head h writes cols h*64..h*64+63
// V LDS layout (swizzled): byte(d, kbyte) = d*528 + (kbyte ^ ((kbyte>>7)&3)<<4)
// where kbyte = 2*(key offset in the 256-key tile). Writes and reads share
// the formula (writer quarter (tid&3) == key-slice bits, reader slice == w).
// ---------------------------------------------------------------------------
__global__ __launch_bounds__(256, 3)
void attn_fwd(const short* __restrict__ Q0, const short* __restrict__ K0,
              const short* __restrict__ Vt0, short* __restrict__ Y0,
              const short* __restrict__ Q1, const short* __restrict__ K1,
              const short* __restrict__ Vt1, short* __restrict__ Y1) {
  __shared__ char ldsraw[37376];
  short* Vs  = (short*)ldsraw;            // 64 rows x 264 shorts (528 B)
  float* Ored = (float*)ldsraw;           // epilogue alias: 3 x 64 x 36 floats
  float* Lred = (float*)(ldsraw + 36864); // 3 x 32 floats

  // XCD swizzle: all 64 q-blocks of one (bh,dir) on one XCD (6 bhd per XCD).
  const int bid  = blockIdx.y * 64 + blockIdx.x;   // 0..3071
  const int xcd  = bid & 7;
  const int slot = bid >> 3;                       // 0..383
  const int bhd  = xcd * 6 + (slot >> 6);          // 0..47 (bijective)
  const int qi   = slot & 63;

  const int dir = bhd >= 24;
  const int bh  = dir ? bhd - 24 : bhd;
  const short* Qg  = dir ? Q1 : Q0;
  const short* Kg  = dir ? K1 : K0;
  const short* Vtg = dir ? Vt1 : Vt0;
  short* Y         = dir ? Y1 : Y0;

  const int tid = threadIdx.x, lane = tid & 63, w = tid >> 6;
  const int c = lane & 15, g = lane >> 4;
  const int b = bh / 12, h = bh % 12;
  const int q0 = qi * 32;

  // Q fragments (B-operand of S^T): lane holds Q[q0+qb*16+c][kk*32 + g*8 + e]
  bf16x8 qf[2][4];
#pragma unroll
  for (int qb = 0; qb < 2; ++qb) {
    const short* qp = Qg + ((size_t)bh * 2048 + q0 + qb * 16 + c) * 128 + g * 8;
#pragma unroll
    for (int kk = 0; kk < 4; ++kk) qf[qb][kk] = *(const bf16x8*)(qp + kk * 32);
  }

  f32x4 o[2][4];
#pragma unroll
  for (int qb = 0; qb < 2; ++qb)
#pragma unroll
    for (int db = 0; db < 4; ++db) o[qb][db] = f32x4{0.f, 0.f, 0.f, 0.f};
  float lsumP[2] = {0.f, 0.f};

  const short* kbase = Kg + (size_t)bh * 2048 * 128;
  const short* vbase = Vtg + (size_t)bh * 64 * 2048;

  // K per-lane base: rows w*64 + j*16 + c, col kk*32 + g*8; +t*256 rows per iter
  const short* kp = kbase + (size_t)(w * 64 + c) * 128 + g * 8;

  // V staging coords: thread covers row vd, key-quarter vq (keys vq*64..+64)
  const int vd = tid >> 2, vq = tid & 3;
  const short* vsrc = vbase + (size_t)vd * 2048 + vq * 64;  // + t*256 + u*8
  short* vdst = Vs + vd * 264 + vq * 64;                    // + (u^vq)*8

  // V read short-offsets (add (db*16+c)*264 at use): key = w*64+kb*32+m*16+g*4
  int voffs[2][2];
#pragma unroll
  for (int kb = 0; kb < 2; ++kb)
#pragma unroll
    for (int m = 0; m < 2; ++m)
      voffs[kb][m] = ((w * 128 + kb * 64 + m * 32 + g * 8) ^ (w << 4)) >> 1;

  bf16x8 vreg[8];
  auto gloadV = [&](int t) {
    const short* s = vsrc + t * 256;
#pragma unroll
    for (int u = 0; u < 8; ++u) vreg[u] = *(const bf16x8*)(s + u * 8);
  };
  auto lwriteV = [&]() {
#pragma unroll
    for (int u = 0; u < 8; ++u) *(bf16x8*)(vdst + ((u ^ vq) * 8)) = vreg[u];
  };
  auto loadK = [&](int t, bf16x8 (&kf)[4][4]) {
    const short* p = kp + (size_t)t * 256 * 128;
#pragma unroll
    for (int j = 0; j < 4; ++j)
#pragma unroll
      for (int kk = 0; kk < 4; ++kk)
        kf[j][kk] = *(const bf16x8*)(p + (size_t)j * 2048 + kk * 32);
  };

  auto body = [&](int t, bf16x8 (&kfC)[4][4], bf16x8 (&kfN)[4][4]) {
    lwriteV();         // publish V tile t (vmcnt waits only on V loads)
    __syncthreads();

    // ---- S^T = K Q^T : st[qb][j] reg r = S[key=16j+4g+r][q=q0+16qb+c] ----
    f32x4 st[2][4] = {};
#pragma unroll
    for (int j = 0; j < 4; ++j)
#pragma unroll
      for (int kk = 0; kk < 4; ++kk) {
        st[0][j] = __builtin_amdgcn_mfma_f32_16x16x32_bf16(kfC[j][kk], qf[0][kk], st[0][j], 0, 0, 0);
        st[1][j] = __builtin_amdgcn_mfma_f32_16x16x32_bf16(kfC[j][kk], qf[1][kk], st[1][j], 0, 0, 0);
      }

    // ---- prefetch tile t+1 (V first so its vmcnt drains first at lwriteV) --
    if (t + 1 < 8) { gloadV(t + 1); loadK(t + 1, kfN); }

    // ---- P = exp2(S) (log2e folded), lsum partial, register pack ----
    bf16x8 pa[2][2];
#pragma unroll
    for (int qb = 0; qb < 2; ++qb) {
      float p[4][4];
#pragma unroll
      for (int j = 0; j < 4; ++j)
#pragma unroll
        for (int r = 0; r < 4; ++r) p[j][r] = exp2f(st[qb][j][r]);
      float s0 = (p[0][0] + p[0][1]) + (p[0][2] + p[0][3]);
      float s1 = (p[1][0] + p[1][1]) + (p[1][2] + p[1][3]);
      float s2 = (p[2][0] + p[2][1]) + (p[2][2] + p[2][3]);
      float s3 = (p[3][0] + p[3][1]) + (p[3][2] + p[3][3]);
      lsumP[qb] += (s0 + s1) + (s2 + s3);
      // pa element u (group g) holds P at key pi(g,u)=32kb+16(u>>2)+4g+(u&3)
#pragma unroll
      for (int kb = 0; kb < 2; ++kb) {
        union { u32x4 u; bf16x8 v; } pk;
        pk.u[0] = cvt_pk_bf16(p[2 * kb][0],     p[2 * kb][1]);
        pk.u[1] = cvt_pk_bf16(p[2 * kb][2],     p[2 * kb][3]);
        pk.u[2] = cvt_pk_bf16(p[2 * kb + 1][0], p[2 * kb + 1][1]);
        pk.u[3] = cvt_pk_bf16(p[2 * kb + 1][2], p[2 * kb + 1][3]);
        pa[qb][kb] = pk.v;
      }
    }

    // ---- O += P V : vf element u = V[w*64 + pi(g,u)][d=db*16+c] ----
#pragma unroll
    for (int kb = 0; kb < 2; ++kb)
#pragma unroll
      for (int db = 0; db < 4; ++db) {
        union { s16x4 hh[2]; bf16x8 v; } vf;
        const short* vrow = Vs + (size_t)(db * 16 + c) * 264;
        vf.hh[0] = *(const s16x4*)(vrow + voffs[kb][0]);
        vf.hh[1] = *(const s16x4*)(vrow + voffs[kb][1]);
        o[0][db] = __builtin_amdgcn_mfma_f32_16x16x32_bf16(pa[0][kb], vf.v, o[0][db], 0, 0, 0);
        o[1][db] = __builtin_amdgcn_mfma_f32_16x16x32_bf16(pa[1][kb], vf.v, o[1][db], 0, 0, 0);
      }
    __syncthreads();   // all waves done reading Vs before next lwriteV
  };

  bf16x8 kfA[4][4], kfB[4][4];
  gloadV(0);
  loadK(0, kfA);
#pragma unroll
  for (int t = 0; t < 8; t += 2) {
    body(t, kfA, kfB);
    body(t + 1, kfB, kfA);
  }

  // ---- cross-wave reduction (partials are exactly additive: fixed max) ----
  float L[2];
#pragma unroll
  for (int qb = 0; qb < 2; ++qb) {
    float v = lsumP[qb];
    v += __shfl_xor(v, 16, 64);
    v += __shfl_xor(v, 32, 64);
    L[qb] = v;   // per-wave lsum(q0 + qb*16 + c), identical across g
  }
  if (w != 0) {
    float* op = Ored + (size_t)(w - 1) * 2304 + lane * 36;
#pragma unroll
    for (int qb = 0; qb < 2; ++qb)
#pragma unroll
      for (int db = 0; db < 4; ++db)
        *(f32x4*)(op + qb * 16 + db * 4) = o[qb][db];
    if (lane < 16) {
      Lred[(w - 1) * 32 + lane]      = L[0];
      Lred[(w - 1) * 32 + 16 + lane] = L[1];
    }
  }
  __syncthreads();
  if (w == 0) {
#pragma unroll
    for (int wp = 0; wp < 3; ++wp) {
      const float* op = Ored + (size_t)wp * 2304 + lane * 36;
#pragma unroll
      for (int qb = 0; qb < 2; ++qb)
#pragma unroll
        for (int db = 0; db < 4; ++db)
          o[qb][db] += *(const f32x4*)(op + qb * 16 + db * 4);
      L[0] += Lred[wp * 32 + c];
      L[1] += Lred[wp * 32 + 16 + c];
    }
    // o[qb][db] reg r = O[q0+qb*16+g*4+r][db*16+c]   (round-5 epilogue)
#pragma unroll
    for (int qb = 0; qb < 2; ++qb) {
      float inv[4];
#pragma unroll
      for (int r = 0; r < 4; ++r)
        inv[r] = 1.0f / __shfl(L[qb], g * 4 + r, 64);
      short* yp = Y + ((size_t)(b * 2048) + q0 + qb * 16 + g * 4) * 768 + h * 64 + c;
#pragma unroll
      for (int db = 0; db < 4; ++db)
#pragma unroll
        for (int r = 0; r < 4; ++r)
          yp[(size_t)r * 768 + db * 16] = f2bf(o[qb][db][r] * inv[r]);
    }
  }
}

// ---------------------------------------------------------------------------
extern "C" void kernel_launch(void* const* d_in, const int* in_sizes, int n_in,
                              void* d_out, int out_size, void* d_ws, size_t ws_size,
                              hipStream_t stream) {
  (void)in_sizes; (void)n_in; (void)out_size; (void)ws_size;

  const float* x     = (const float*)d_in[0];
  const float* srcp  = (const float*)d_in[1];
  const float* qk_w  = (const float*)d_in[2];
  const float* qks_w = (const float*)d_in[3];
  const float* v_w   = (const float*)d_in[4];
  const float* vs_w  = (const float*)d_in[5];
  const float* p_w   = (const float*)d_in[6];
  const float* p_b   = (const float*)d_in[7];
  const float* ps_w  = (const float*)d_in[8];
  const float* ps_b  = (const float*)d_in[9];
  float* out = (float*)d_out;

  char* ws = (char*)d_ws;
  size_t off = 0;
  auto alloc = [&](size_t elems) -> short* {
    short* p = (short*)(ws + off);
    off += (elems * 2 + 255) & ~(size_t)255;
    return p;
  };
  // NOTE: first 8 allocations are written by cvt_all as one flat segment.
  short* xb    = alloc(4096UL * 768);
  short* sb    = alloc(4096UL * 768);
  short* qkwb  = alloc(1536UL * 768);
  short* qkswb = alloc(1536UL * 768);
  short* vwb   = alloc(768UL * 768);
  short* vswb  = alloc(768UL * 768);
  short* pwb   = alloc(768UL * 768);
  short* pswb  = alloc(768UL * 768);
  short* qk    = alloc(24UL * 2048 * 128);  // [B,H,N,128], 0.125*log2e folded
  short* qks   = alloc(24UL * 2048 * 128);
  short* vT    = alloc(24UL * 64 * 2048);   // [B,H,64,N]
  short* vsT   = alloc(24UL * 64 * 2048);
  short* y     = alloc(4096UL * 768);
  short* ysv   = alloc(4096UL * 768);

  // fused fp32->bf16 (2752512 float4 groups == 10752 blocks exactly)
  cvt_all<<<dim3(10752), dim3(256), 0, stream>>>(x, srcp, qk_w, qks_w, v_w, vs_w,
                                                 p_w, ps_w, xb);

  // input projections (both problems per dispatch)
  gemm_bt2<EPI_HEAD128><<<dim3(12, 64), 256, 0, stream>>>(
      xb, qkwb, qk, nullptr, sb, qkswb, qks, nullptr, nullptr);
  gemm_bt2<EPI_HEADT64><<<dim3(6, 64), 256, 0, stream>>>(
      xb, vwb, vT, nullptr, sb, vswb, vsT, nullptr, nullptr);

  // bidirectional attention: key-split waves, 32 q / block, XCD-swizzled
  attn_fwd<<<dim3(64, 48), 256, 0, stream>>>(qk, qks, vsT, y,
                                             qks, qk, vT, ysv);

  // output projections into concatenated fp32 output [B, 2048, 1536]
  gemm_bt2<EPI_PROJ><<<dim3(6, 64), 256, 0, stream>>>(
      y, pwb, nullptr, p_b, ysv, pswb, nullptr, ps_b, out);
}

// Round 11
// 201.389 us; speedup vs baseline: 3.2591x; 3.2591x over previous
//
#include <hip/hip_runtime.h>
#include <hip/hip_bf16.h>
#include <cstdint>
#include <cstddef>

// ---------------------------------------------------------------------------
// BidirectionalCrossAttention — MI355X bf16 MFMA implementation, round 11.
// attn_fwd = round-5 kernel EXACTLY (best measured: 137 µs, 5 later variants
// all regressed). GEMM change only: HEADT64 / PROJ move to 64-row tiles so
// their grids go 384 -> 768 blocks (1.5 -> 3 blocks/CU machine utilization).
// ---------------------------------------------------------------------------

typedef __attribute__((ext_vector_type(4))) float f32x4;
typedef __attribute__((ext_vector_type(8))) short bf16x8;
typedef __attribute__((ext_vector_type(4))) short s16x4;
typedef __attribute__((ext_vector_type(4))) unsigned int u32x4;

__device__ __forceinline__ short f2bf(float f) {
  union { float f; unsigned u; } v; v.f = f;
  unsigned r = v.u + 0x7FFF + ((v.u >> 16) & 1);   // RNE
  return (short)(r >> 16);
}

__device__ __forceinline__ unsigned cvt_pk_bf16(float lo, float hi) {
  unsigned r;
  asm("v_cvt_pk_bf16_f32 %0, %1, %2" : "=v"(r) : "v"(lo), "v"(hi));
  return r;   // D[15:0]=bf16(lo), D[31:16]=bf16(hi)
}

__device__ __forceinline__ void async16(const void* g, void* l) {
  __builtin_amdgcn_global_load_lds(
      (__attribute__((address_space(1))) unsigned int*)(g),
      (__attribute__((address_space(3))) unsigned int*)(l),
      16, 0, 0);
}

// ---------------------------------------------------------------------------
// Fused fp32 -> bf16 conversion over the 8 inputs (round-4 proven).
// ---------------------------------------------------------------------------
__global__ __launch_bounds__(256)
void cvt_all(const float* __restrict__ x, const float* __restrict__ src,
             const float* __restrict__ qkw, const float* __restrict__ qksw,
             const float* __restrict__ vw, const float* __restrict__ vsw,
             const float* __restrict__ pw, const float* __restrict__ psw,
             short* __restrict__ out) {
  int i = blockIdx.x * 256 + threadIdx.x;
  const float* in; int local; float scale = 1.f;
  if (i < 1572864) {
    if (i < 786432) { in = x; local = i; } else { in = src; local = i - 786432; }
  } else if (i < 2162688) {
    if (i < 1867776) { in = qkw; local = i - 1572864; scale = 0.125f * 1.44269504f; }
    else             { in = qksw; local = i - 1867776; }
  } else if (i < 2457600) {
    if (i < 2310144) { in = vw; local = i - 2162688; } else { in = vsw; local = i - 2310144; }
  } else {
    if (i < 2605056) { in = pw; local = i - 2457600; } else { in = psw; local = i - 2605056; }
  }
  float4 v = ((const float4*)in)[local];
  s16x4 o = { f2bf(v.x * scale), f2bf(v.y * scale),
              f2bf(v.z * scale), f2bf(v.w * scale) };
  ((s16x4*)out)[i] = o;
}

// ---------------------------------------------------------------------------
// GEMM: out[row, f] = sum_c A[row,c] * W[f,c]   (K = 768, round-4 proven core)
// TR = tile rows (128 or 64). Col tile fixed at 128. Two problems/dispatch.
//   TR=128: grid (cols/128, 2*rows/128), 4 async16/thread/iter, acc[4][4]
//   TR=64 : grid (cols/128, 2*rows/64),  3 async16/thread/iter, acc[2][4]
// ---------------------------------------------------------------------------
enum { EPI_HEAD128 = 0, EPI_HEADT64 = 1, EPI_PROJ = 2 };

template<int EPI, int TR>
__global__ __launch_bounds__(256)
void gemm_bt2(const short* __restrict__ A0, const short* __restrict__ W0,
              short* __restrict__ ob0, const float* __restrict__ bias0,
              const short* __restrict__ A1, const short* __restrict__ W1,
              short* __restrict__ ob1, const float* __restrict__ bias1,
              float* __restrict__ outf) {
  __shared__ short As[TR * 32];
  __shared__ short Ws[128 * 32];

  constexpr int NI = TR / 32;          // row sub-tiles per wave (4 or 2)
  const int sel = (TR == 128) ? (blockIdx.y >> 5) : (blockIdx.y >> 6);
  const int by  = (TR == 128) ? (blockIdx.y & 31) : (blockIdx.y & 63);
  const short* A = sel ? A1 : A0;
  const short* W = sel ? W1 : W0;
  short* outb = sel ? ob1 : ob0;
  const float* bias = sel ? bias1 : bias0;
  const int outColOff = sel ? 768 : 0;

  const int tid  = threadIdx.x;
  const int lane = tid & 63, wid = tid >> 6;
  const int wr = wid >> 1, wc = wid & 1;
  const int rowBase = by * TR, colBase = blockIdx.x << 7;
  const int c = lane & 15, g = lane >> 4;

  constexpr int AROWS = (TR == 128) ? 32 : 16;   // rows staged per wave
  const short* gA = A + (size_t)(rowBase + wid * AROWS + (lane >> 2)) * 768 + (lane & 3) * 8;
  const short* gW = W + (size_t)(colBase + wid * 32 + (lane >> 2)) * 768 + (lane & 3) * 8;
  short* lA = As + wid * AROWS * 32;
  short* lW = Ws + wid * 32 * 32;

  const short* rA = As + (wr * (TR / 2) + c) * 32 + g * 8;
  const short* rW = Ws + (wc * 64 + c) * 32 + g * 8;

  f32x4 acc[NI][4] = {};

  for (int kt = 0; kt < 24; ++kt) {
    async16(gA, lA);
    if (TR == 128) async16(gA + 16 * 768, lA + 16 * 32);
    async16(gW,            lW);
    async16(gW + 16 * 768, lW + 16 * 32);
    gA += 32; gW += 32;
    __syncthreads();
    bf16x8 af[NI], wf[4];
#pragma unroll
    for (int i = 0; i < NI; ++i) af[i] = *(const bf16x8*)(rA + i * 512);
#pragma unroll
    for (int j = 0; j < 4; ++j) wf[j] = *(const bf16x8*)(rW + j * 512);
#pragma unroll
    for (int i = 0; i < NI; ++i)
#pragma unroll
      for (int j = 0; j < 4; ++j)
        acc[i][j] = __builtin_amdgcn_mfma_f32_16x16x32_bf16(af[i], wf[j], acc[i][j], 0, 0, 0);
    __syncthreads();
  }

  if (EPI == EPI_HEAD128) {
#pragma unroll
    for (int i = 0; i < NI; ++i) {
      int row = rowBase + wr * (TR / 2) + i * 16 + g * 4;
      int b = row >> 11, n = row & 2047;
#pragma unroll
      for (int j = 0; j < 4; ++j) {
        int f = colBase + wc * 64 + j * 16 + c;
        int h = f >> 7, d = f & 127;
        short* p = outb + ((size_t)(b * 12 + h) * 2048 + n) * 128 + d;
#pragma unroll
        for (int r = 0; r < 4; ++r) p[(size_t)r * 128] = f2bf(acc[i][j][r]);
      }
    }
  } else if (EPI == EPI_HEADT64) {
#pragma unroll
    for (int i = 0; i < NI; ++i) {
      int row = rowBase + wr * (TR / 2) + i * 16 + g * 4;
      int b = row >> 11, n = row & 2047;
#pragma unroll
      for (int j = 0; j < 4; ++j) {
        int f = colBase + wc * 64 + j * 16 + c;
        int h = f >> 6, d = f & 63;
        s16x4 o4 = { f2bf(acc[i][j][0]), f2bf(acc[i][j][1]),
                     f2bf(acc[i][j][2]), f2bf(acc[i][j][3]) };
        *(s16x4*)(outb + ((size_t)(b * 12 + h) * 64 + d) * 2048 + n) = o4;
      }
    }
  } else {  // EPI_PROJ
#pragma unroll
    for (int j = 0; j < 4; ++j) {
      int colj = colBase + wc * 64 + j * 16 + c;
      float bv = bias[colj];
#pragma unroll
      for (int i = 0; i < NI; ++i) {
        int row = rowBase + wr * (TR / 2) + i * 16 + g * 4;
#pragma unroll
        for (int r = 0; r < 4; ++r)
          outf[(size_t)(row + r) * 1536 + outColOff + colj] = acc[i][j][r] + bv;
      }
    }
  }
}

// ---------------------------------------------------------------------------
// Flash cross-attention, BOTH directions in one dispatch (dir = blockIdx.y/24).
// ROUND-5 KERNEL, byte-identical. Swapped QK^T: lane holds P[q=c][16 keys];
// register-P via cvt_pk with k-slot bijection pi(g,u)=32kb+16(u>>2)+4g+(u&3)
// shared by the P pack and the V reads.
//   Q : [BH, 2048, 128] bf16   K : [BH, 2048, 128] bf16
//   Vt: [BH, 64, 2048]  bf16 (V transposed)
//   Y : [B, 2048, 768]  bf16, head h writes cols h*64..h*64+63
// ---------------------------------------------------------------------------
__global__ __launch_bounds__(256)
void attn_fwd(const short* __restrict__ Q0, const short* __restrict__ K0,
              const short* __restrict__ Vt0, short* __restrict__ Y0,
              const short* __restrict__ Q1, const short* __restrict__ K1,
              const short* __restrict__ Vt1, short* __restrict__ Y1) {
  __shared__ short Ks[64 * 136];    // [64 keys][128 dims], stride 136
  __shared__ short Vs[64 * 72];     // [64 dims][64 keys],  stride 72

  const int dir = blockIdx.y >= 24;
  const int bh  = dir ? blockIdx.y - 24 : blockIdx.y;
  const short* Qg  = dir ? Q1 : Q0;
  const short* Kg  = dir ? K1 : K0;
  const short* Vtg = dir ? Vt1 : Vt0;
  short* Y         = dir ? Y1 : Y0;

  const int tid = threadIdx.x, lane = tid & 63, wid = tid >> 6;
  const int c = lane & 15, g = lane >> 4;
  const int b = bh / 12, h = bh % 12;
  const int q0 = blockIdx.x * 128 + wid * 32;

  // Q fragments (B-operand of S^T): lane holds Q[q0+qb*16+c][kk*32 + g*8 + e]
  bf16x8 qf[2][4];
#pragma unroll
  for (int qb = 0; qb < 2; ++qb) {
    const short* qp = Qg + ((size_t)bh * 2048 + q0 + qb * 16 + c) * 128 + g * 8;
#pragma unroll
    for (int kk = 0; kk < 4; ++kk) qf[qb][kk] = *(const bf16x8*)(qp + kk * 32);
  }

  f32x4 o[2][4];
#pragma unroll
  for (int qb = 0; qb < 2; ++qb)
#pragma unroll
    for (int db = 0; db < 4; ++db) o[qb][db] = f32x4{0.f, 0.f, 0.f, 0.f};
  float lsumP[2] = {0.f, 0.f};

  const short* kbase = Kg + (size_t)bh * 2048 * 128;
  const short* vbase = Vtg + (size_t)bh * 64 * 2048;

  // per-thread staging coordinates (round-5 exact pattern)
  const int srow = tid >> 2, scc = (tid & 3) * 32, skc = (tid & 3) * 16;

  bf16x8 kreg[4], vreg[2];   // prefetch registers
  auto gload = [&](int kt) {
    const short* srcK = kbase + ((size_t)(kt * 64 + srow)) * 128 + scc;
#pragma unroll
    for (int u = 0; u < 4; ++u) kreg[u] = *(const bf16x8*)(srcK + u * 8);
    const short* srcV = vbase + (size_t)srow * 2048 + kt * 64 + skc;
    vreg[0] = *(const bf16x8*)(srcV);
    vreg[1] = *(const bf16x8*)(srcV + 8);
  };
  auto lwrite = [&]() {
    short* dstK = Ks + srow * 136 + scc;
#pragma unroll
    for (int u = 0; u < 4; ++u) *(bf16x8*)(dstK + u * 8) = kreg[u];
    short* dstV = Vs + srow * 72 + skc;
    *(bf16x8*)(dstV)     = vreg[0];
    *(bf16x8*)(dstV + 8) = vreg[1];
  };

  gload(0);
  for (int kt = 0; kt < 32; ++kt) {
    lwrite();          // write tile kt (regs -> LDS); vmcnt wait lands here
    __syncthreads();   // tile kt visible to all waves

    // ---- S^T = K Q^T : st[qb][j] reg r = S[key=16j+4g+r][q=q0+16qb+c] ----
    f32x4 st[2][4];
#pragma unroll
    for (int qb = 0; qb < 2; ++qb)
#pragma unroll
      for (int j = 0; j < 4; ++j) st[qb][j] = f32x4{0.f, 0.f, 0.f, 0.f};
#pragma unroll
    for (int j = 0; j < 4; ++j)
#pragma unroll
      for (int kk = 0; kk < 4; ++kk) {
        bf16x8 kf = *(const bf16x8*)(Ks + (j * 16 + c) * 136 + kk * 32 + g * 8);
        st[0][j] = __builtin_amdgcn_mfma_f32_16x16x32_bf16(kf, qf[0][kk], st[0][j], 0, 0, 0);
        st[1][j] = __builtin_amdgcn_mfma_f32_16x16x32_bf16(kf, qf[1][kk], st[1][j], 0, 0, 0);
      }

    // ---- P = exp2(S) (log2e folded), lsum partial, register pack ----
    bf16x8 pa[2][2];
#pragma unroll
    for (int qb = 0; qb < 2; ++qb) {
      float p[4][4];
#pragma unroll
      for (int j = 0; j < 4; ++j)
#pragma unroll
        for (int r = 0; r < 4; ++r) p[j][r] = exp2f(st[qb][j][r]);
      float s0 = (p[0][0] + p[0][1]) + (p[0][2] + p[0][3]);
      float s1 = (p[1][0] + p[1][1]) + (p[1][2] + p[1][3]);
      float s2 = (p[2][0] + p[2][1]) + (p[2][2] + p[2][3]);
      float s3 = (p[3][0] + p[3][1]) + (p[3][2] + p[3][3]);
      lsumP[qb] += (s0 + s1) + (s2 + s3);
      // pa element u (lane group g) holds P at key pi(g,u)=32kb+16(u>>2)+4g+(u&3)
#pragma unroll
      for (int kb = 0; kb < 2; ++kb) {
        union { u32x4 u; bf16x8 v; } pk;
        pk.u[0] = cvt_pk_bf16(p[2 * kb][0],     p[2 * kb][1]);
        pk.u[1] = cvt_pk_bf16(p[2 * kb][2],     p[2 * kb][3]);
        pk.u[2] = cvt_pk_bf16(p[2 * kb + 1][0], p[2 * kb + 1][1]);
        pk.u[3] = cvt_pk_bf16(p[2 * kb + 1][2], p[2 * kb + 1][3]);
        pa[qb][kb] = pk.v;
      }
    }

    if (kt + 1 < 32) gload(kt + 1);   // T14: prefetch hides under PV + barrier

    // ---- O += P V : vf element u = V[pi(g,u)][d=db*16+c] (same pi) ----
#pragma unroll
    for (int kb = 0; kb < 2; ++kb)
#pragma unroll
      for (int db = 0; db < 4; ++db) {
        union { s16x4 h[2]; bf16x8 v; } vf;
        const short* vrow = Vs + (size_t)(db * 16 + c) * 72 + kb * 32 + g * 4;
        vf.h[0] = *(const s16x4*)(vrow);
        vf.h[1] = *(const s16x4*)(vrow + 16);
        o[0][db] = __builtin_amdgcn_mfma_f32_16x16x32_bf16(pa[0][kb], vf.v, o[0][db], 0, 0, 0);
        o[1][db] = __builtin_amdgcn_mfma_f32_16x16x32_bf16(pa[1][kb], vf.v, o[1][db], 0, 0, 0);
      }
    __syncthreads();   // LDS reads done before next iteration's lwrite
  }

  // ---- epilogue: lsum reduce over the 4 g-groups (same q = c lanes) ----
  float L[2];
#pragma unroll
  for (int qb = 0; qb < 2; ++qb) {
    float v = lsumP[qb];
    v += __shfl_xor(v, 16, 64);
    v += __shfl_xor(v, 32, 64);
    L[qb] = v;   // lsum(q0 + qb*16 + c), identical across g
  }
  // o[qb][db] reg r = O[q0+qb*16+g*4+r][db*16+c]
#pragma unroll
  for (int qb = 0; qb < 2; ++qb) {
    float inv[4];
#pragma unroll
    for (int r = 0; r < 4; ++r)
      inv[r] = 1.0f / __shfl(L[qb], g * 4 + r, 64);
    short* yp = Y + ((size_t)(b * 2048) + q0 + qb * 16 + g * 4) * 768 + h * 64 + c;
#pragma unroll
    for (int db = 0; db < 4; ++db)
#pragma unroll
      for (int r = 0; r < 4; ++r)
        yp[(size_t)r * 768 + db * 16] = f2bf(o[qb][db][r] * inv[r]);
  }
}

// ---------------------------------------------------------------------------
extern "C" void kernel_launch(void* const* d_in, const int* in_sizes, int n_in,
                              void* d_out, int out_size, void* d_ws, size_t ws_size,
                              hipStream_t stream) {
  (void)in_sizes; (void)n_in; (void)out_size; (void)ws_size;

  const float* x     = (const float*)d_in[0];
  const float* srcp  = (const float*)d_in[1];
  const float* qk_w  = (const float*)d_in[2];
  const float* qks_w = (const float*)d_in[3];
  const float* v_w   = (const float*)d_in[4];
  const float* vs_w  = (const float*)d_in[5];
  const float* p_w   = (const float*)d_in[6];
  const float* p_b   = (const float*)d_in[7];
  const float* ps_w  = (const float*)d_in[8];
  const float* ps_b  = (const float*)d_in[9];
  float* out = (float*)d_out;

  char* ws = (char*)d_ws;
  size_t off = 0;
  auto alloc = [&](size_t elems) -> short* {
    short* p = (short*)(ws + off);
    off += (elems * 2 + 255) & ~(size_t)255;
    return p;
  };
  // NOTE: first 8 allocations are written by cvt_all as one flat segment.
  short* xb    = alloc(4096UL * 768);
  short* sb    = alloc(4096UL * 768);
  short* qkwb  = alloc(1536UL * 768);
  short* qkswb = alloc(1536UL * 768);
  short* vwb   = alloc(768UL * 768);
  short* vswb  = alloc(768UL * 768);
  short* pwb   = alloc(768UL * 768);
  short* pswb  = alloc(768UL * 768);
  short* qk    = alloc(24UL * 2048 * 128);  // [B,H,N,128], 0.125*log2e folded
  short* qks   = alloc(24UL * 2048 * 128);
  short* vT    = alloc(24UL * 64 * 2048);   // [B,H,64,N]
  short* vsT   = alloc(24UL * 64 * 2048);
  short* y     = alloc(4096UL * 768);
  short* ysv   = alloc(4096UL * 768);

  // fused fp32->bf16 (2752512 float4 groups == 10752 blocks exactly)
  cvt_all<<<dim3(10752), dim3(256), 0, stream>>>(x, srcp, qk_w, qks_w, v_w, vs_w,
                                                 p_w, ps_w, xb);

  // input projections (both problems per dispatch)
  gemm_bt2<EPI_HEAD128, 128><<<dim3(12, 64), 256, 0, stream>>>(
      xb, qkwb, qk, nullptr, sb, qkswb, qks, nullptr, nullptr);
  gemm_bt2<EPI_HEADT64, 64><<<dim3(6, 128), 256, 0, stream>>>(
      xb, vwb, vT, nullptr, sb, vswb, vsT, nullptr, nullptr);

  // bidirectional attention: both directions in one dispatch (round-5 kernel)
  attn_fwd<<<dim3(16, 48), 256, 0, stream>>>(qk, qks, vsT, y,
                                             qks, qk, vT, ysv);

  // output projections into concatenated fp32 output [B, 2048, 1536]
  gemm_bt2<EPI_PROJ, 64><<<dim3(6, 128), 256, 0, stream>>>(
      y, pwb, nullptr, p_b, ysv, pswb, nullptr, ps_b, out);
}

// Round 12
// 197.069 us; speedup vs baseline: 3.3305x; 1.0219x over previous
//
#include <hip/hip_runtime.h>
#include <hip/hip_bf16.h>
#include <cstdint>
#include <cstddef>

// ---------------------------------------------------------------------------
// BidirectionalCrossAttention — MI355X bf16 MFMA implementation, round 12.
// attn_fwd = round-5 kernel byte-identical (137 µs, best of 7 variants).
// Change this round: HEAD128 + HEADT64 input projections merged into ONE
// 1536-block dispatch (launch-gap + tail overlap); shared gemm_core body.
// ---------------------------------------------------------------------------

typedef __attribute__((ext_vector_type(4))) float f32x4;
typedef __attribute__((ext_vector_type(8))) short bf16x8;
typedef __attribute__((ext_vector_type(4))) short s16x4;
typedef __attribute__((ext_vector_type(4))) unsigned int u32x4;

__device__ __forceinline__ short f2bf(float f) {
  union { float f; unsigned u; } v; v.f = f;
  unsigned r = v.u + 0x7FFF + ((v.u >> 16) & 1);   // RNE
  return (short)(r >> 16);
}

__device__ __forceinline__ unsigned cvt_pk_bf16(float lo, float hi) {
  unsigned r;
  asm("v_cvt_pk_bf16_f32 %0, %1, %2" : "=v"(r) : "v"(lo), "v"(hi));
  return r;   // D[15:0]=bf16(lo), D[31:16]=bf16(hi)
}

__device__ __forceinline__ void async16(const void* g, void* l) {
  __builtin_amdgcn_global_load_lds(
      (__attribute__((address_space(1))) unsigned int*)(g),
      (__attribute__((address_space(3))) unsigned int*)(l),
      16, 0, 0);
}

// ---------------------------------------------------------------------------
// Fused fp32 -> bf16 conversion over the 8 inputs (round-4 proven).
// ---------------------------------------------------------------------------
__global__ __launch_bounds__(256)
void cvt_all(const float* __restrict__ x, const float* __restrict__ src,
             const float* __restrict__ qkw, const float* __restrict__ qksw,
             const float* __restrict__ vw, const float* __restrict__ vsw,
             const float* __restrict__ pw, const float* __restrict__ psw,
             short* __restrict__ out) {
  int i = blockIdx.x * 256 + threadIdx.x;
  const float* in; int local; float scale = 1.f;
  if (i < 1572864) {
    if (i < 786432) { in = x; local = i; } else { in = src; local = i - 786432; }
  } else if (i < 2162688) {
    if (i < 1867776) { in = qkw; local = i - 1572864; scale = 0.125f * 1.44269504f; }
    else             { in = qksw; local = i - 1867776; }
  } else if (i < 2457600) {
    if (i < 2310144) { in = vw; local = i - 2162688; } else { in = vsw; local = i - 2310144; }
  } else {
    if (i < 2605056) { in = pw; local = i - 2457600; } else { in = psw; local = i - 2605056; }
  }
  float4 v = ((const float4*)in)[local];
  s16x4 o = { f2bf(v.x * scale), f2bf(v.y * scale),
              f2bf(v.z * scale), f2bf(v.w * scale) };
  ((s16x4*)out)[i] = o;
}

// ---------------------------------------------------------------------------
// GEMM core: out[row, f] = sum_c A[row,c] * W[f,c]  (K = 768, r11-proven body)
// TR = tile rows (128 or 64). Col tile 128. Caller resolves problem pointers.
// ---------------------------------------------------------------------------
enum { EPI_HEAD128 = 0, EPI_HEADT64 = 1, EPI_PROJ = 2 };

template<int EPI, int TR>
__device__ __forceinline__
void gemm_core(short* As, short* Ws,
               const short* __restrict__ A, const short* __restrict__ W,
               short* __restrict__ outb, const float* __restrict__ bias,
               float* __restrict__ outf, int outColOff, int bx, int by) {
  constexpr int NI = TR / 32;          // row sub-tiles per wave (4 or 2)
  const int tid  = threadIdx.x;
  const int lane = tid & 63, wid = tid >> 6;
  const int wr = wid >> 1, wc = wid & 1;
  const int rowBase = by * TR, colBase = bx << 7;
  const int c = lane & 15, g = lane >> 4;

  constexpr int AROWS = (TR == 128) ? 32 : 16;   // rows staged per wave
  const short* gA = A + (size_t)(rowBase + wid * AROWS + (lane >> 2)) * 768 + (lane & 3) * 8;
  const short* gW = W + (size_t)(colBase + wid * 32 + (lane >> 2)) * 768 + (lane & 3) * 8;
  short* lA = As + wid * AROWS * 32;
  short* lW = Ws + wid * 32 * 32;

  const short* rA = As + (wr * (TR / 2) + c) * 32 + g * 8;
  const short* rW = Ws + (wc * 64 + c) * 32 + g * 8;

  f32x4 acc[NI][4] = {};

  for (int kt = 0; kt < 24; ++kt) {
    async16(gA, lA);
    if (TR == 128) async16(gA + 16 * 768, lA + 16 * 32);
    async16(gW,            lW);
    async16(gW + 16 * 768, lW + 16 * 32);
    gA += 32; gW += 32;
    __syncthreads();
    bf16x8 af[NI], wf[4];
#pragma unroll
    for (int i = 0; i < NI; ++i) af[i] = *(const bf16x8*)(rA + i * 512);
#pragma unroll
    for (int j = 0; j < 4; ++j) wf[j] = *(const bf16x8*)(rW + j * 512);
#pragma unroll
    for (int i = 0; i < NI; ++i)
#pragma unroll
      for (int j = 0; j < 4; ++j)
        acc[i][j] = __builtin_amdgcn_mfma_f32_16x16x32_bf16(af[i], wf[j], acc[i][j], 0, 0, 0);
    __syncthreads();
  }

  if (EPI == EPI_HEAD128) {
#pragma unroll
    for (int i = 0; i < NI; ++i) {
      int row = rowBase + wr * (TR / 2) + i * 16 + g * 4;
      int b = row >> 11, n = row & 2047;
#pragma unroll
      for (int j = 0; j < 4; ++j) {
        int f = colBase + wc * 64 + j * 16 + c;
        int h = f >> 7, d = f & 127;
        short* p = outb + ((size_t)(b * 12 + h) * 2048 + n) * 128 + d;
#pragma unroll
        for (int r = 0; r < 4; ++r) p[(size_t)r * 128] = f2bf(acc[i][j][r]);
      }
    }
  } else if (EPI == EPI_HEADT64) {
#pragma unroll
    for (int i = 0; i < NI; ++i) {
      int row = rowBase + wr * (TR / 2) + i * 16 + g * 4;
      int b = row >> 11, n = row & 2047;
#pragma unroll
      for (int j = 0; j < 4; ++j) {
        int f = colBase + wc * 64 + j * 16 + c;
        int h = f >> 6, d = f & 63;
        s16x4 o4 = { f2bf(acc[i][j][0]), f2bf(acc[i][j][1]),
                     f2bf(acc[i][j][2]), f2bf(acc[i][j][3]) };
        *(s16x4*)(outb + ((size_t)(b * 12 + h) * 64 + d) * 2048 + n) = o4;
      }
    }
  } else {  // EPI_PROJ
#pragma unroll
    for (int j = 0; j < 4; ++j) {
      int colj = colBase + wc * 64 + j * 16 + c;
      float bv = bias[colj];
#pragma unroll
      for (int i = 0; i < NI; ++i) {
        int row = rowBase + wr * (TR / 2) + i * 16 + g * 4;
#pragma unroll
        for (int r = 0; r < 4; ++r)
          outf[(size_t)(row + r) * 1536 + outColOff + colj] = acc[i][j][r] + bv;
      }
    }
  }
}

// Fused input projections: blocks [0,768) = HEAD128 (qk / qk_src),
// blocks [768,1536) = HEADT64 (v / v_src transposed). 1-D grid, even 6/CU.
__global__ __launch_bounds__(256)
void gemm_in_fused(const short* __restrict__ xb, const short* __restrict__ qkwb,
                   short* __restrict__ qk, const short* __restrict__ sb,
                   const short* __restrict__ qkswb, short* __restrict__ qks,
                   const short* __restrict__ vwb, short* __restrict__ vT,
                   const short* __restrict__ vswb, short* __restrict__ vsT) {
  __shared__ short As[128 * 32];
  __shared__ short Ws[128 * 32];
  const int bid = blockIdx.x;
  if (bid < 768) {
    const int bx = bid % 12, y = bid / 12;       // grid (12, 64) decode
    const int sel = y >> 5, by = y & 31;
    gemm_core<EPI_HEAD128, 128>(As, Ws, sel ? sb : xb, sel ? qkswb : qkwb,
                                sel ? qks : qk, nullptr, nullptr, 0, bx, by);
  } else {
    const int t = bid - 768;
    const int bx = t % 6, y = t / 6;             // grid (6, 128) decode
    const int sel = y >> 6, by = y & 63;
    gemm_core<EPI_HEADT64, 64>(As, Ws, sel ? sb : xb, sel ? vswb : vwb,
                               sel ? vsT : vT, nullptr, nullptr, 0, bx, by);
  }
}

// Output projection (depends on attn; separate dispatch), r11-proven geometry.
__global__ __launch_bounds__(256)
void gemm_proj(const short* __restrict__ A0, const short* __restrict__ W0,
               const float* __restrict__ bias0,
               const short* __restrict__ A1, const short* __restrict__ W1,
               const float* __restrict__ bias1, float* __restrict__ outf) {
  __shared__ short As[64 * 32];
  __shared__ short Ws[128 * 32];
  const int sel = blockIdx.y >> 6;
  const int by  = blockIdx.y & 63;
  gemm_core<EPI_PROJ, 64>(As, Ws, sel ? A1 : A0, sel ? W1 : W0, nullptr,
                          sel ? bias1 : bias0, outf, sel ? 768 : 0,
                          blockIdx.x, by);
}

// ---------------------------------------------------------------------------
// Flash cross-attention, BOTH directions in one dispatch (dir = blockIdx.y/24).
// ROUND-5 KERNEL, byte-identical. Swapped QK^T: lane holds P[q=c][16 keys];
// register-P via cvt_pk with k-slot bijection pi(g,u)=32kb+16(u>>2)+4g+(u&3)
// shared by the P pack and the V reads.
//   Q : [BH, 2048, 128] bf16   K : [BH, 2048, 128] bf16
//   Vt: [BH, 64, 2048]  bf16 (V transposed)
//   Y : [B, 2048, 768]  bf16, head h writes cols h*64..h*64+63
// ---------------------------------------------------------------------------
__global__ __launch_bounds__(256)
void attn_fwd(const short* __restrict__ Q0, const short* __restrict__ K0,
              const short* __restrict__ Vt0, short* __restrict__ Y0,
              const short* __restrict__ Q1, const short* __restrict__ K1,
              const short* __restrict__ Vt1, short* __restrict__ Y1) {
  __shared__ short Ks[64 * 136];    // [64 keys][128 dims], stride 136
  __shared__ short Vs[64 * 72];     // [64 dims][64 keys],  stride 72

  const int dir = blockIdx.y >= 24;
  const int bh  = dir ? blockIdx.y - 24 : blockIdx.y;
  const short* Qg  = dir ? Q1 : Q0;
  const short* Kg  = dir ? K1 : K0;
  const short* Vtg = dir ? Vt1 : Vt0;
  short* Y         = dir ? Y1 : Y0;

  const int tid = threadIdx.x, lane = tid & 63, wid = tid >> 6;
  const int c = lane & 15, g = lane >> 4;
  const int b = bh / 12, h = bh % 12;
  const int q0 = blockIdx.x * 128 + wid * 32;

  // Q fragments (B-operand of S^T): lane holds Q[q0+qb*16+c][kk*32 + g*8 + e]
  bf16x8 qf[2][4];
#pragma unroll
  for (int qb = 0; qb < 2; ++qb) {
    const short* qp = Qg + ((size_t)bh * 2048 + q0 + qb * 16 + c) * 128 + g * 8;
#pragma unroll
    for (int kk = 0; kk < 4; ++kk) qf[qb][kk] = *(const bf16x8*)(qp + kk * 32);
  }

  f32x4 o[2][4];
#pragma unroll
  for (int qb = 0; qb < 2; ++qb)
#pragma unroll
    for (int db = 0; db < 4; ++db) o[qb][db] = f32x4{0.f, 0.f, 0.f, 0.f};
  float lsumP[2] = {0.f, 0.f};

  const short* kbase = Kg + (size_t)bh * 2048 * 128;
  const short* vbase = Vtg + (size_t)bh * 64 * 2048;

  // per-thread staging coordinates (round-5 exact pattern)
  const int srow = tid >> 2, scc = (tid & 3) * 32, skc = (tid & 3) * 16;

  bf16x8 kreg[4], vreg[2];   // prefetch registers
  auto gload = [&](int kt) {
    const short* srcK = kbase + ((size_t)(kt * 64 + srow)) * 128 + scc;
#pragma unroll
    for (int u = 0; u < 4; ++u) kreg[u] = *(const bf16x8*)(srcK + u * 8);
    const short* srcV = vbase + (size_t)srow * 2048 + kt * 64 + skc;
    vreg[0] = *(const bf16x8*)(srcV);
    vreg[1] = *(const bf16x8*)(srcV + 8);
  };
  auto lwrite = [&]() {
    short* dstK = Ks + srow * 136 + scc;
#pragma unroll
    for (int u = 0; u < 4; ++u) *(bf16x8*)(dstK + u * 8) = kreg[u];
    short* dstV = Vs + srow * 72 + skc;
    *(bf16x8*)(dstV)     = vreg[0];
    *(bf16x8*)(dstV + 8) = vreg[1];
  };

  gload(0);
  for (int kt = 0; kt < 32; ++kt) {
    lwrite();          // write tile kt (regs -> LDS); vmcnt wait lands here
    __syncthreads();   // tile kt visible to all waves

    // ---- S^T = K Q^T : st[qb][j] reg r = S[key=16j+4g+r][q=q0+16qb+c] ----
    f32x4 st[2][4];
#pragma unroll
    for (int qb = 0; qb < 2; ++qb)
#pragma unroll
      for (int j = 0; j < 4; ++j) st[qb][j] = f32x4{0.f, 0.f, 0.f, 0.f};
#pragma unroll
    for (int j = 0; j < 4; ++j)
#pragma unroll
      for (int kk = 0; kk < 4; ++kk) {
        bf16x8 kf = *(const bf16x8*)(Ks + (j * 16 + c) * 136 + kk * 32 + g * 8);
        st[0][j] = __builtin_amdgcn_mfma_f32_16x16x32_bf16(kf, qf[0][kk], st[0][j], 0, 0, 0);
        st[1][j] = __builtin_amdgcn_mfma_f32_16x16x32_bf16(kf, qf[1][kk], st[1][j], 0, 0, 0);
      }

    // ---- P = exp2(S) (log2e folded), lsum partial, register pack ----
    bf16x8 pa[2][2];
#pragma unroll
    for (int qb = 0; qb < 2; ++qb) {
      float p[4][4];
#pragma unroll
      for (int j = 0; j < 4; ++j)
#pragma unroll
        for (int r = 0; r < 4; ++r) p[j][r] = exp2f(st[qb][j][r]);
      float s0 = (p[0][0] + p[0][1]) + (p[0][2] + p[0][3]);
      float s1 = (p[1][0] + p[1][1]) + (p[1][2] + p[1][3]);
      float s2 = (p[2][0] + p[2][1]) + (p[2][2] + p[2][3]);
      float s3 = (p[3][0] + p[3][1]) + (p[3][2] + p[3][3]);
      lsumP[qb] += (s0 + s1) + (s2 + s3);
      // pa element u (lane group g) holds P at key pi(g,u)=32kb+16(u>>2)+4g+(u&3)
#pragma unroll
      for (int kb = 0; kb < 2; ++kb) {
        union { u32x4 u; bf16x8 v; } pk;
        pk.u[0] = cvt_pk_bf16(p[2 * kb][0],     p[2 * kb][1]);
        pk.u[1] = cvt_pk_bf16(p[2 * kb][2],     p[2 * kb][3]);
        pk.u[2] = cvt_pk_bf16(p[2 * kb + 1][0], p[2 * kb + 1][1]);
        pk.u[3] = cvt_pk_bf16(p[2 * kb + 1][2], p[2 * kb + 1][3]);
        pa[qb][kb] = pk.v;
      }
    }

    if (kt + 1 < 32) gload(kt + 1);   // T14: prefetch hides under PV + barrier

    // ---- O += P V : vf element u = V[pi(g,u)][d=db*16+c] (same pi) ----
#pragma unroll
    for (int kb = 0; kb < 2; ++kb)
#pragma unroll
      for (int db = 0; db < 4; ++db) {
        union { s16x4 h[2]; bf16x8 v; } vf;
        const short* vrow = Vs + (size_t)(db * 16 + c) * 72 + kb * 32 + g * 4;
        vf.h[0] = *(const s16x4*)(vrow);
        vf.h[1] = *(const s16x4*)(vrow + 16);
        o[0][db] = __builtin_amdgcn_mfma_f32_16x16x32_bf16(pa[0][kb], vf.v, o[0][db], 0, 0, 0);
        o[1][db] = __builtin_amdgcn_mfma_f32_16x16x32_bf16(pa[1][kb], vf.v, o[1][db], 0, 0, 0);
      }
    __syncthreads();   // LDS reads done before next iteration's lwrite
  }

  // ---- epilogue: lsum reduce over the 4 g-groups (same q = c lanes) ----
  float L[2];
#pragma unroll
  for (int qb = 0; qb < 2; ++qb) {
    float v = lsumP[qb];
    v += __shfl_xor(v, 16, 64);
    v += __shfl_xor(v, 32, 64);
    L[qb] = v;   // lsum(q0 + qb*16 + c), identical across g
  }
  // o[qb][db] reg r = O[q0+qb*16+g*4+r][db*16+c]
#pragma unroll
  for (int qb = 0; qb < 2; ++qb) {
    float inv[4];
#pragma unroll
    for (int r = 0; r < 4; ++r)
      inv[r] = 1.0f / __shfl(L[qb], g * 4 + r, 64);
    short* yp = Y + ((size_t)(b * 2048) + q0 + qb * 16 + g * 4) * 768 + h * 64 + c;
#pragma unroll
    for (int db = 0; db < 4; ++db)
#pragma unroll
      for (int r = 0; r < 4; ++r)
        yp[(size_t)r * 768 + db * 16] = f2bf(o[qb][db][r] * inv[r]);
  }
}

// ---------------------------------------------------------------------------
extern "C" void kernel_launch(void* const* d_in, const int* in_sizes, int n_in,
                              void* d_out, int out_size, void* d_ws, size_t ws_size,
                              hipStream_t stream) {
  (void)in_sizes; (void)n_in; (void)out_size; (void)ws_size;

  const float* x     = (const float*)d_in[0];
  const float* srcp  = (const float*)d_in[1];
  const float* qk_w  = (const float*)d_in[2];
  const float* qks_w = (const float*)d_in[3];
  const float* v_w   = (const float*)d_in[4];
  const float* vs_w  = (const float*)d_in[5];
  const float* p_w   = (const float*)d_in[6];
  const float* p_b   = (const float*)d_in[7];
  const float* ps_w  = (const float*)d_in[8];
  const float* ps_b  = (const float*)d_in[9];
  float* out = (float*)d_out;

  char* ws = (char*)d_ws;
  size_t off = 0;
  auto alloc = [&](size_t elems) -> short* {
    short* p = (short*)(ws + off);
    off += (elems * 2 + 255) & ~(size_t)255;
    return p;
  };
  // NOTE: first 8 allocations are written by cvt_all as one flat segment.
  short* xb    = alloc(4096UL * 768);
  short* sb    = alloc(4096UL * 768);
  short* qkwb  = alloc(1536UL * 768);
  short* qkswb = alloc(1536UL * 768);
  short* vwb   = alloc(768UL * 768);
  short* vswb  = alloc(768UL * 768);
  short* pwb   = alloc(768UL * 768);
  short* pswb  = alloc(768UL * 768);
  short* qk    = alloc(24UL * 2048 * 128);  // [B,H,N,128], 0.125*log2e folded
  short* qks   = alloc(24UL * 2048 * 128);
  short* vT    = alloc(24UL * 64 * 2048);   // [B,H,64,N]
  short* vsT   = alloc(24UL * 64 * 2048);
  short* y     = alloc(4096UL * 768);
  short* ysv   = alloc(4096UL * 768);

  // fused fp32->bf16 (2752512 float4 groups == 10752 blocks exactly)
  cvt_all<<<dim3(10752), dim3(256), 0, stream>>>(x, srcp, qk_w, qks_w, v_w, vs_w,
                                                 p_w, ps_w, xb);

  // ALL input projections in one 1536-block dispatch (HEAD128 + HEADT64)
  gemm_in_fused<<<dim3(1536), 256, 0, stream>>>(xb, qkwb, qk, sb, qkswb, qks,
                                                vwb, vT, vswb, vsT);

  // bidirectional attention: both directions in one dispatch (round-5 kernel)
  attn_fwd<<<dim3(16, 48), 256, 0, stream>>>(qk, qks, vsT, y,
                                             qks, qk, vT, ysv);

  // output projections into concatenated fp32 output [B, 2048, 1536]
  gemm_proj<<<dim3(6, 128), 256, 0, stream>>>(y, pwb, p_b, ysv, pswb, ps_b, out);
}

// Round 13
// 187.164 us; speedup vs baseline: 3.5068x; 1.0529x over previous
//
#include <hip/hip_runtime.h>
#include <hip/hip_bf16.h>
#include <cstdint>
#include <cstddef>

// ---------------------------------------------------------------------------
// BidirectionalCrossAttention — MI355X bf16 MFMA implementation, round 13.
// attn_fwd = round-5 kernel with ONE change: V stored in LDS pre-permuted
// with kappa(key)=32kb+8G+4j+r so each lane's PV B-fragment is a single
// b128 read (was 2 XOR-free b64s at 4-way bank conflict). Writes become
// 4 x b64 at 2 lanes/bank (free per m136). Bit-identical math.
// GEMM stack = round-12 (fused input projections).
// ---------------------------------------------------------------------------

typedef __attribute__((ext_vector_type(4))) float f32x4;
typedef __attribute__((ext_vector_type(8))) short bf16x8;
typedef __attribute__((ext_vector_type(4))) short s16x4;
typedef __attribute__((ext_vector_type(4))) unsigned int u32x4;

__device__ __forceinline__ short f2bf(float f) {
  union { float f; unsigned u; } v; v.f = f;
  unsigned r = v.u + 0x7FFF + ((v.u >> 16) & 1);   // RNE
  return (short)(r >> 16);
}

__device__ __forceinline__ unsigned cvt_pk_bf16(float lo, float hi) {
  unsigned r;
  asm("v_cvt_pk_bf16_f32 %0, %1, %2" : "=v"(r) : "v"(lo), "v"(hi));
  return r;   // D[15:0]=bf16(lo), D[31:16]=bf16(hi)
}

__device__ __forceinline__ void async16(const void* g, void* l) {
  __builtin_amdgcn_global_load_lds(
      (__attribute__((address_space(1))) unsigned int*)(g),
      (__attribute__((address_space(3))) unsigned int*)(l),
      16, 0, 0);
}

// ---------------------------------------------------------------------------
// Fused fp32 -> bf16 conversion over the 8 inputs (round-4 proven).
// ---------------------------------------------------------------------------
__global__ __launch_bounds__(256)
void cvt_all(const float* __restrict__ x, const float* __restrict__ src,
             const float* __restrict__ qkw, const float* __restrict__ qksw,
             const float* __restrict__ vw, const float* __restrict__ vsw,
             const float* __restrict__ pw, const float* __restrict__ psw,
             short* __restrict__ out) {
  int i = blockIdx.x * 256 + threadIdx.x;
  const float* in; int local; float scale = 1.f;
  if (i < 1572864) {
    if (i < 786432) { in = x; local = i; } else { in = src; local = i - 786432; }
  } else if (i < 2162688) {
    if (i < 1867776) { in = qkw; local = i - 1572864; scale = 0.125f * 1.44269504f; }
    else             { in = qksw; local = i - 1867776; }
  } else if (i < 2457600) {
    if (i < 2310144) { in = vw; local = i - 2162688; } else { in = vsw; local = i - 2310144; }
  } else {
    if (i < 2605056) { in = pw; local = i - 2457600; } else { in = psw; local = i - 2605056; }
  }
  float4 v = ((const float4*)in)[local];
  s16x4 o = { f2bf(v.x * scale), f2bf(v.y * scale),
              f2bf(v.z * scale), f2bf(v.w * scale) };
  ((s16x4*)out)[i] = o;
}

// ---------------------------------------------------------------------------
// GEMM core: out[row, f] = sum_c A[row,c] * W[f,c]  (K = 768, r11-proven body)
// ---------------------------------------------------------------------------
enum { EPI_HEAD128 = 0, EPI_HEADT64 = 1, EPI_PROJ = 2 };

template<int EPI, int TR>
__device__ __forceinline__
void gemm_core(short* As, short* Ws,
               const short* __restrict__ A, const short* __restrict__ W,
               short* __restrict__ outb, const float* __restrict__ bias,
               float* __restrict__ outf, int outColOff, int bx, int by) {
  constexpr int NI = TR / 32;          // row sub-tiles per wave (4 or 2)
  const int tid  = threadIdx.x;
  const int lane = tid & 63, wid = tid >> 6;
  const int wr = wid >> 1, wc = wid & 1;
  const int rowBase = by * TR, colBase = bx << 7;
  const int c = lane & 15, g = lane >> 4;

  constexpr int AROWS = (TR == 128) ? 32 : 16;   // rows staged per wave
  const short* gA = A + (size_t)(rowBase + wid * AROWS + (lane >> 2)) * 768 + (lane & 3) * 8;
  const short* gW = W + (size_t)(colBase + wid * 32 + (lane >> 2)) * 768 + (lane & 3) * 8;
  short* lA = As + wid * AROWS * 32;
  short* lW = Ws + wid * 32 * 32;

  const short* rA = As + (wr * (TR / 2) + c) * 32 + g * 8;
  const short* rW = Ws + (wc * 64 + c) * 32 + g * 8;

  f32x4 acc[NI][4] = {};

  for (int kt = 0; kt < 24; ++kt) {
    async16(gA, lA);
    if (TR == 128) async16(gA + 16 * 768, lA + 16 * 32);
    async16(gW,            lW);
    async16(gW + 16 * 768, lW + 16 * 32);
    gA += 32; gW += 32;
    __syncthreads();
    bf16x8 af[NI], wf[4];
#pragma unroll
    for (int i = 0; i < NI; ++i) af[i] = *(const bf16x8*)(rA + i * 512);
#pragma unroll
    for (int j = 0; j < 4; ++j) wf[j] = *(const bf16x8*)(rW + j * 512);
#pragma unroll
    for (int i = 0; i < NI; ++i)
#pragma unroll
      for (int j = 0; j < 4; ++j)
        acc[i][j] = __builtin_amdgcn_mfma_f32_16x16x32_bf16(af[i], wf[j], acc[i][j], 0, 0, 0);
    __syncthreads();
  }

  if (EPI == EPI_HEAD128) {
#pragma unroll
    for (int i = 0; i < NI; ++i) {
      int row = rowBase + wr * (TR / 2) + i * 16 + g * 4;
      int b = row >> 11, n = row & 2047;
#pragma unroll
      for (int j = 0; j < 4; ++j) {
        int f = colBase + wc * 64 + j * 16 + c;
        int h = f >> 7, d = f & 127;
        short* p = outb + ((size_t)(b * 12 + h) * 2048 + n) * 128 + d;
#pragma unroll
        for (int r = 0; r < 4; ++r) p[(size_t)r * 128] = f2bf(acc[i][j][r]);
      }
    }
  } else if (EPI == EPI_HEADT64) {
#pragma unroll
    for (int i = 0; i < NI; ++i) {
      int row = rowBase + wr * (TR / 2) + i * 16 + g * 4;
      int b = row >> 11, n = row & 2047;
#pragma unroll
      for (int j = 0; j < 4; ++j) {
        int f = colBase + wc * 64 + j * 16 + c;
        int h = f >> 6, d = f & 63;
        s16x4 o4 = { f2bf(acc[i][j][0]), f2bf(acc[i][j][1]),
                     f2bf(acc[i][j][2]), f2bf(acc[i][j][3]) };
        *(s16x4*)(outb + ((size_t)(b * 12 + h) * 64 + d) * 2048 + n) = o4;
      }
    }
  } else {  // EPI_PROJ
#pragma unroll
    for (int j = 0; j < 4; ++j) {
      int colj = colBase + wc * 64 + j * 16 + c;
      float bv = bias[colj];
#pragma unroll
      for (int i = 0; i < NI; ++i) {
        int row = rowBase + wr * (TR / 2) + i * 16 + g * 4;
#pragma unroll
        for (int r = 0; r < 4; ++r)
          outf[(size_t)(row + r) * 1536 + outColOff + colj] = acc[i][j][r] + bv;
      }
    }
  }
}

// Fused input projections: blocks [0,768) = HEAD128, [768,1536) = HEADT64.
__global__ __launch_bounds__(256)
void gemm_in_fused(const short* __restrict__ xb, const short* __restrict__ qkwb,
                   short* __restrict__ qk, const short* __restrict__ sb,
                   const short* __restrict__ qkswb, short* __restrict__ qks,
                   const short* __restrict__ vwb, short* __restrict__ vT,
                   const short* __restrict__ vswb, short* __restrict__ vsT) {
  __shared__ short As[128 * 32];
  __shared__ short Ws[128 * 32];
  const int bid = blockIdx.x;
  if (bid < 768) {
    const int bx = bid % 12, y = bid / 12;       // grid (12, 64) decode
    const int sel = y >> 5, by = y & 31;
    gemm_core<EPI_HEAD128, 128>(As, Ws, sel ? sb : xb, sel ? qkswb : qkwb,
                                sel ? qks : qk, nullptr, nullptr, 0, bx, by);
  } else {
    const int t = bid - 768;
    const int bx = t % 6, y = t / 6;             // grid (6, 128) decode
    const int sel = y >> 6, by = y & 63;
    gemm_core<EPI_HEADT64, 64>(As, Ws, sel ? sb : xb, sel ? vswb : vwb,
                               sel ? vsT : vT, nullptr, nullptr, 0, bx, by);
  }
}

// Output projection (depends on attn; separate dispatch), r11-proven geometry.
__global__ __launch_bounds__(256)
void gemm_proj(const short* __restrict__ A0, const short* __restrict__ W0,
               const float* __restrict__ bias0,
               const short* __restrict__ A1, const short* __restrict__ W1,
               const float* __restrict__ bias1, float* __restrict__ outf) {
  __shared__ short As[64 * 32];
  __shared__ short Ws[128 * 32];
  const int sel = blockIdx.y >> 6;
  const int by  = blockIdx.y & 63;
  gemm_core<EPI_PROJ, 64>(As, Ws, sel ? A1 : A0, sel ? W1 : W0, nullptr,
                          sel ? bias1 : bias0, outf, sel ? 768 : 0,
                          blockIdx.x, by);
}

// ---------------------------------------------------------------------------
// Flash cross-attention, BOTH directions in one dispatch (dir = blockIdx.y/24).
// Round-5 maps; V LDS layout permuted: key k=32kb+16j+4G+r stored at
// kappa(k)=32kb+8G+4j+r, so the PV B-fragment (keys pi(g,u)) is ONE b128 at
// kappa = 32kb+8g (since kappa(pi(g,u)) = 32kb+8g+u).
//   Q : [BH, 2048, 128] bf16   K : [BH, 2048, 128] bf16
//   Vt: [BH, 64, 2048]  bf16 (V transposed)
//   Y : [B, 2048, 768]  bf16, head h writes cols h*64..h*64+63
// ---------------------------------------------------------------------------
__global__ __launch_bounds__(256)
void attn_fwd(const short* __restrict__ Q0, const short* __restrict__ K0,
              const short* __restrict__ Vt0, short* __restrict__ Y0,
              const short* __restrict__ Q1, const short* __restrict__ K1,
              const short* __restrict__ Vt1, short* __restrict__ Y1) {
  __shared__ short Ks[64 * 136];    // [64 keys][128 dims], stride 136
  __shared__ short Vs[64 * 72];     // [64 dims][64 kappa-slots], stride 72

  const int dir = blockIdx.y >= 24;
  const int bh  = dir ? blockIdx.y - 24 : blockIdx.y;
  const short* Qg  = dir ? Q1 : Q0;
  const short* Kg  = dir ? K1 : K0;
  const short* Vtg = dir ? Vt1 : Vt0;
  short* Y         = dir ? Y1 : Y0;

  const int tid = threadIdx.x, lane = tid & 63, wid = tid >> 6;
  const int c = lane & 15, g = lane >> 4;
  const int b = bh / 12, h = bh % 12;
  const int q0 = blockIdx.x * 128 + wid * 32;

  // Q fragments (B-operand of S^T): lane holds Q[q0+qb*16+c][kk*32 + g*8 + e]
  bf16x8 qf[2][4];
#pragma unroll
  for (int qb = 0; qb < 2; ++qb) {
    const short* qp = Qg + ((size_t)bh * 2048 + q0 + qb * 16 + c) * 128 + g * 8;
#pragma unroll
    for (int kk = 0; kk < 4; ++kk) qf[qb][kk] = *(const bf16x8*)(qp + kk * 32);
  }

  f32x4 o[2][4];
#pragma unroll
  for (int qb = 0; qb < 2; ++qb)
#pragma unroll
    for (int db = 0; db < 4; ++db) o[qb][db] = f32x4{0.f, 0.f, 0.f, 0.f};
  float lsumP[2] = {0.f, 0.f};

  const short* kbase = Kg + (size_t)bh * 2048 * 128;
  const short* vbase = Vtg + (size_t)bh * 64 * 2048;

  // staging coords: K rows srow, 32-short cols scc; V row srow, 16 keys at skc
  const int srow = tid >> 2, scc = (tid & 3) * 32, skc = (tid & 3) * 16;
  // kappa decomposition of this thread's 16 keys: kb=(tid&3)>>1, j=(tid&3)&1
  const int vkb = (tid & 3) >> 1, vj = (tid & 3) & 1;
  short* vdst = Vs + srow * 72 + vkb * 32 + vj * 4;   // + 8*G + r

  bf16x8 kreg[4], vreg[2];   // prefetch registers
  auto gload = [&](int kt) {
    const short* srcK = kbase + ((size_t)(kt * 64 + srow)) * 128 + scc;
#pragma unroll
    for (int u = 0; u < 4; ++u) kreg[u] = *(const bf16x8*)(srcK + u * 8);
    const short* srcV = vbase + (size_t)srow * 2048 + kt * 64 + skc;
    vreg[0] = *(const bf16x8*)(srcV);
    vreg[1] = *(const bf16x8*)(srcV + 8);
  };
  auto lwrite = [&]() {
    short* dstK = Ks + srow * 136 + scc;
#pragma unroll
    for (int u = 0; u < 4; ++u) *(bf16x8*)(dstK + u * 8) = kreg[u];
    // V permuted write: key skc+4G+r -> kappa = vkb*32 + 8G + 4vj + r
    union { bf16x8 v[2]; s16x4 q[4]; } uv;
    uv.v[0] = vreg[0]; uv.v[1] = vreg[1];
#pragma unroll
    for (int G = 0; G < 4; ++G) *(s16x4*)(vdst + 8 * G) = uv.q[G];
  };

  gload(0);
  for (int kt = 0; kt < 32; ++kt) {
    lwrite();          // write tile kt (regs -> LDS); vmcnt wait lands here
    __syncthreads();   // tile kt visible to all waves

    // ---- S^T = K Q^T : st[qb][j] reg r = S[key=16j+4g+r][q=q0+16qb+c] ----
    f32x4 st[2][4];
#pragma unroll
    for (int qb = 0; qb < 2; ++qb)
#pragma unroll
      for (int j = 0; j < 4; ++j) st[qb][j] = f32x4{0.f, 0.f, 0.f, 0.f};
#pragma unroll
    for (int j = 0; j < 4; ++j)
#pragma unroll
      for (int kk = 0; kk < 4; ++kk) {
        bf16x8 kf = *(const bf16x8*)(Ks + (j * 16 + c) * 136 + kk * 32 + g * 8);
        st[0][j] = __builtin_amdgcn_mfma_f32_16x16x32_bf16(kf, qf[0][kk], st[0][j], 0, 0, 0);
        st[1][j] = __builtin_amdgcn_mfma_f32_16x16x32_bf16(kf, qf[1][kk], st[1][j], 0, 0, 0);
      }

    // ---- P = exp2(S) (log2e folded), lsum partial, register pack ----
    bf16x8 pa[2][2];
#pragma unroll
    for (int qb = 0; qb < 2; ++qb) {
      float p[4][4];
#pragma unroll
      for (int j = 0; j < 4; ++j)
#pragma unroll
        for (int r = 0; r < 4; ++r) p[j][r] = exp2f(st[qb][j][r]);
      float s0 = (p[0][0] + p[0][1]) + (p[0][2] + p[0][3]);
      float s1 = (p[1][0] + p[1][1]) + (p[1][2] + p[1][3]);
      float s2 = (p[2][0] + p[2][1]) + (p[2][2] + p[2][3]);
      float s3 = (p[3][0] + p[3][1]) + (p[3][2] + p[3][3]);
      lsumP[qb] += (s0 + s1) + (s2 + s3);
      // pa element u (lane group g) holds P at key pi(g,u)=32kb+16(u>>2)+4g+(u&3)
#pragma unroll
      for (int kb = 0; kb < 2; ++kb) {
        union { u32x4 u; bf16x8 v; } pk;
        pk.u[0] = cvt_pk_bf16(p[2 * kb][0],     p[2 * kb][1]);
        pk.u[1] = cvt_pk_bf16(p[2 * kb][2],     p[2 * kb][3]);
        pk.u[2] = cvt_pk_bf16(p[2 * kb + 1][0], p[2 * kb + 1][1]);
        pk.u[3] = cvt_pk_bf16(p[2 * kb + 1][2], p[2 * kb + 1][3]);
        pa[qb][kb] = pk.v;
      }
    }

    if (kt + 1 < 32) gload(kt + 1);   // T14: prefetch hides under PV + barrier

    // ---- O += P V : vf = single b128 at kappa = 32kb + 8g (pre-permuted) ----
#pragma unroll
    for (int kb = 0; kb < 2; ++kb)
#pragma unroll
      for (int db = 0; db < 4; ++db) {
        bf16x8 vf = *(const bf16x8*)(Vs + (size_t)(db * 16 + c) * 72 + kb * 32 + g * 8);
        o[0][db] = __builtin_amdgcn_mfma_f32_16x16x32_bf16(pa[0][kb], vf, o[0][db], 0, 0, 0);
        o[1][db] = __builtin_amdgcn_mfma_f32_16x16x32_bf16(pa[1][kb], vf, o[1][db], 0, 0, 0);
      }
    __syncthreads();   // LDS reads done before next iteration's lwrite
  }

  // ---- epilogue: lsum reduce over the 4 g-groups (same q = c lanes) ----
  float L[2];
#pragma unroll
  for (int qb = 0; qb < 2; ++qb) {
    float v = lsumP[qb];
    v += __shfl_xor(v, 16, 64);
    v += __shfl_xor(v, 32, 64);
    L[qb] = v;   // lsum(q0 + qb*16 + c), identical across g
  }
  // o[qb][db] reg r = O[q0+qb*16+g*4+r][db*16+c]
#pragma unroll
  for (int qb = 0; qb < 2; ++qb) {
    float inv[4];
#pragma unroll
    for (int r = 0; r < 4; ++r)
      inv[r] = 1.0f / __shfl(L[qb], g * 4 + r, 64);
    short* yp = Y + ((size_t)(b * 2048) + q0 + qb * 16 + g * 4) * 768 + h * 64 + c;
#pragma unroll
    for (int db = 0; db < 4; ++db)
#pragma unroll
      for (int r = 0; r < 4; ++r)
        yp[(size_t)r * 768 + db * 16] = f2bf(o[qb][db][r] * inv[r]);
  }
}

// ---------------------------------------------------------------------------
extern "C" void kernel_launch(void* const* d_in, const int* in_sizes, int n_in,
                              void* d_out, int out_size, void* d_ws, size_t ws_size,
                              hipStream_t stream) {
  (void)in_sizes; (void)n_in; (void)out_size; (void)ws_size;

  const float* x     = (const float*)d_in[0];
  const float* srcp  = (const float*)d_in[1];
  const float* qk_w  = (const float*)d_in[2];
  const float* qks_w = (const float*)d_in[3];
  const float* v_w   = (const float*)d_in[4];
  const float* vs_w  = (const float*)d_in[5];
  const float* p_w   = (const float*)d_in[6];
  const float* p_b   = (const float*)d_in[7];
  const float* ps_w  = (const float*)d_in[8];
  const float* ps_b  = (const float*)d_in[9];
  float* out = (float*)d_out;

  char* ws = (char*)d_ws;
  size_t off = 0;
  auto alloc = [&](size_t elems) -> short* {
    short* p = (short*)(ws + off);
    off += (elems * 2 + 255) & ~(size_t)255;
    return p;
  };
  // NOTE: first 8 allocations are written by cvt_all as one flat segment.
  short* xb    = alloc(4096UL * 768);
  short* sb    = alloc(4096UL * 768);
  short* qkwb  = alloc(1536UL * 768);
  short* qkswb = alloc(1536UL * 768);
  short* vwb   = alloc(768UL * 768);
  short* vswb  = alloc(768UL * 768);
  short* pwb   = alloc(768UL * 768);
  short* pswb  = alloc(768UL * 768);
  short* qk    = alloc(24UL * 2048 * 128);  // [B,H,N,128], 0.125*log2e folded
  short* qks   = alloc(24UL * 2048 * 128);
  short* vT    = alloc(24UL * 64 * 2048);   // [B,H,64,N]
  short* vsT   = alloc(24UL * 64 * 2048);
  short* y     = alloc(4096UL * 768);
  short* ysv   = alloc(4096UL * 768);

  // fused fp32->bf16 (2752512 float4 groups == 10752 blocks exactly)
  cvt_all<<<dim3(10752), dim3(256), 0, stream>>>(x, srcp, qk_w, qks_w, v_w, vs_w,
                                                 p_w, ps_w, xb);

  // ALL input projections in one 1536-block dispatch (HEAD128 + HEADT64)
  gemm_in_fused<<<dim3(1536), 256, 0, stream>>>(xb, qkwb, qk, sb, qkswb, qks,
                                                vwb, vT, vswb, vsT);

  // bidirectional attention: both directions in one dispatch
  attn_fwd<<<dim3(16, 48), 256, 0, stream>>>(qk, qks, vsT, y,
                                             qks, qk, vT, ysv);

  // output projections into concatenated fp32 output [B, 2048, 1536]
  gemm_proj<<<dim3(6, 128), 256, 0, stream>>>(y, pwb, p_b, ysv, pswb, ps_b, out);
}